// Round 7
// baseline (268.908 us; speedup 1.0000x reference)
//
#include <hip/hip_runtime.h>
#include <stdint.h>

#define GAS __attribute__((address_space(1)))
#define LAS __attribute__((address_space(3)))

typedef __attribute__((ext_vector_type(8))) __bf16 bf16x8;
typedef __attribute__((ext_vector_type(4))) float f32x4;

static constexpr int Bb = 4, Ll = 2048, Dd = 512, Hh = 8, DHd = 64;
static constexpr float LOG2E = 1.4426950408889634f;

__device__ __forceinline__ unsigned short f2bf(float f){
  unsigned u = __float_as_uint(f);
  u += 0x7fffu + ((u >> 16) & 1u);           // round-to-nearest-even
  return (unsigned short)(u >> 16);
}
__device__ __forceinline__ void gload16(const void* g, void* l){
  __builtin_amdgcn_global_load_lds((const GAS void*)g, (LAS void*)l, 16, 0, 0);
}
__device__ __forceinline__ f32x4 mfma16(bf16x8 a, bf16x8 b, f32x4 c){
  return __builtin_amdgcn_mfma_f32_16x16x32_bf16(a, b, c, 0, 0, 0);
}
__device__ __forceinline__ float exp2_hw(float x){   // v_exp_f32 = 2^x
  float r; asm("v_exp_f32 %0, %1" : "=v"(r) : "v"(x)); return r;
}

// ---------------------------------------------------------------------------
// row sum-of-squares + f32 -> bf16 cast.  grid = B*L, block = 256 (2 elems/thr)
__global__ __launch_bounds__(256) void sumsq_cast(const float* __restrict__ x,
                                                  unsigned short* __restrict__ xbf,
                                                  float* __restrict__ sq){
  int row = blockIdx.x, tid = threadIdx.x;
  float2 v = ((const float2*)(x + (size_t)row * Dd))[tid];
  ((unsigned*)(xbf + (size_t)row * Dd))[tid] =
      (unsigned)f2bf(v.x) | ((unsigned)f2bf(v.y) << 16);
  float s2 = v.x * v.x + v.y * v.y;
  #pragma unroll
  for (int t = 1; t < 64; t <<= 1) s2 += __shfl_xor(s2, t, 64);
  __shared__ float red[4];
  if ((tid & 63) == 0) red[tid >> 6] = s2;
  __syncthreads();
  if (tid == 0) sq[row] = red[0] + red[1] + red[2] + red[3];
}

// ---------------------------------------------------------------------------
// all six weight transposes in ONE launch.  f32 (R,C) -> bf16 (C,R).
// wq/wk/wv land in the CONCATENATED wqkvT (1536 x 512) for the fused QKV gemm.
__global__ void transpose_all(
    const float* __restrict__ wq, const float* __restrict__ wk,
    const float* __restrict__ wv, const float* __restrict__ wo,
    const float* __restrict__ w1, const float* __restrict__ w2,
    unsigned short* __restrict__ wqkvT, unsigned short* __restrict__ woT,
    unsigned short* __restrict__ w1T, unsigned short* __restrict__ w2T)
{
  __shared__ float t[32][33];
  int bid = blockIdx.x;
  const float* in; unsigned short* out; int R, C, bx, by;
  if (bid < 1024){
    int s = bid >> 8, tt = bid & 255;
    in  = s == 0 ? wq : s == 1 ? wk : s == 2 ? wv : wo;
    out = s == 3 ? woT : wqkvT + s * 512 * 512;
    R = 512; C = 512; bx = tt & 15; by = tt >> 4;
  } else if (bid < 2048){
    int tt = bid - 1024; in = w1; out = w1T; R = 512; C = 2048; bx = tt & 63; by = tt >> 6;
  } else {
    int tt = bid - 2048; in = w2; out = w2T; R = 2048; C = 512; bx = tt & 15; by = tt >> 4;
  }
  int tx = threadIdx.x, ty = threadIdx.y;
  int c0 = bx * 32, r0 = by * 32;
  #pragma unroll
  for (int j = 0; j < 32; j += 8) t[ty + j][tx] = in[(size_t)(r0 + ty + j) * C + c0 + tx];
  __syncthreads();
  #pragma unroll
  for (int j = 0; j < 32; j += 8) out[(size_t)(c0 + ty + j) * R + r0 + tx] = f2bf(t[tx][ty + j]);
}

// ---------------------------------------------------------------------------
// 128x128x64 bf16 MFMA GEMM, B transposed (N,K) row-major, 2-phase LDS dbuf.
// MODE 0: TRIANGULAR gram/cdist (grid.x = 136 upper-tri tiles, z = batch);
//         stores cdm' = cd*LOG2E*mask + 8 (fixed-m softmax offset folded in),
//         writes BOTH triangles (transposed via packed uint2), atomicMax rmax
//         from row-dir AND col-dir maxes.
// MODE 2/4: +bias +extra -> f32      MODE 3: relu(+bias) -> bf16
// MODE 5: fused QKV -> bf16; v-slice (cols>=1024) written TRANSPOSED into vT
//         (passed via outf) as (b,h,dh,l).
template<int MODE>
__global__ __launch_bounds__(256) void gemm_bt(
    const unsigned short* __restrict__ A,
    const unsigned short* __restrict__ Bt,
    int M, int N, int K,
    const float* __restrict__ bias,
    const float* __restrict__ extra,
    float* __restrict__ outf,
    unsigned short* __restrict__ outb,
    const float* __restrict__ sq,
    float* __restrict__ rmax,
    const float* __restrict__ mask,
    const float* __restrict__ bias_k,
    const float* __restrict__ bias_v)
{
  int m0, n0, bxx = 0, byy = 0;
  if (MODE == 0){
    int z = blockIdx.z;
    A    += (size_t)z * Ll * Dd;
    Bt    = A;
    outb += (size_t)z * Ll * Ll;
    sq += z * Ll; rmax += z * Ll; mask += z * Ll;
    int tt = blockIdx.x, byv = 0;
    while (tt >= 16 - byv){ tt -= 16 - byv; byv++; }
    byy = byv; bxx = byv + tt;
    m0 = byy * 128; n0 = bxx * 128;
  } else {
    m0 = blockIdx.y * 128; n0 = blockIdx.x * 128;
  }
  const int tid = threadIdx.x, w = tid >> 6, l = tid & 63;
  const int wm = w >> 1, wn = w & 1;
  __shared__ unsigned short lA[2][128 * 64];
  __shared__ unsigned short lB[2][128 * 64];
  f32x4 acc[4][4];
  const f32x4 z4 = {0.f, 0.f, 0.f, 0.f};
  #pragma unroll
  for (int i = 0; i < 4; i++){
    #pragma unroll
    for (int j = 0; j < 4; j++) acc[i][j] = z4;
  }
  const int srow = w * 8 + (l >> 3);
  const int sc = l & 7;

  // prologue: stage k-tile 0 into buffer 0
  #pragma unroll
  for (int j = 0; j < 4; j++){
    int row = j * 32 + srow;
    gload16(A + (size_t)(m0 + row) * K + ((sc ^ (row & 7)) << 3),
            &lA[0][0] + j * 2048 + w * 512);
    gload16(Bt + (size_t)(n0 + row) * K + ((sc ^ (row & 7)) << 3),
            &lB[0][0] + j * 2048 + w * 512);
  }
  __syncthreads();

  int cur = 0;
  for (int k0 = 0; k0 < K; k0 += 64, cur ^= 1){
    if (k0 + 64 < K){               // stage next k-tile first (overlaps compute)
      #pragma unroll
      for (int j = 0; j < 4; j++){
        int row = j * 32 + srow;
        gload16(A + (size_t)(m0 + row) * K + k0 + 64 + ((sc ^ (row & 7)) << 3),
                &lA[cur ^ 1][0] + j * 2048 + w * 512);
        gload16(Bt + (size_t)(n0 + row) * K + k0 + 64 + ((sc ^ (row & 7)) << 3),
                &lB[cur ^ 1][0] + j * 2048 + w * 512);
      }
    }
    bf16x8 af[4][2], bv[4][2];
    #pragma unroll
    for (int kk = 0; kk < 2; kk++){
      #pragma unroll
      for (int f = 0; f < 4; f++){
        int ra = wm * 64 + f * 16 + (l & 15);
        af[f][kk] = *(const bf16x8*)((const char*)&lA[cur][0] + ra * 128 +
                      (((kk * 4 + (l >> 4)) ^ (ra & 7)) << 4));
        int rb = wn * 64 + f * 16 + (l & 15);
        bv[f][kk] = *(const bf16x8*)((const char*)&lB[cur][0] + rb * 128 +
                      (((kk * 4 + (l >> 4)) ^ (rb & 7)) << 4));
      }
    }
    #pragma unroll
    for (int mf = 0; mf < 4; mf++){
      #pragma unroll
      for (int nf = 0; nf < 4; nf++){
        #pragma unroll
        for (int kk = 0; kk < 2; kk++)
          acc[mf][nf] = mfma16(af[mf][kk], bv[nf][kk], acc[mf][nf]);
      }
    }
    __syncthreads();   // staged t+1 landed; everyone done reading buf[cur]
  }

  if (MODE == 0){
    // transform acc in place: stored value = cd*LOG2E*mask + 8
    float sqc[4], mkc[4];
    #pragma unroll
    for (int nf = 0; nf < 4; nf++){
      int col = n0 + wn * 64 + nf * 16 + (l & 15);
      sqc[nf] = sq[col]; mkc[nf] = mask[col];
    }
    #pragma unroll
    for (int mf = 0; mf < 4; mf++){
      #pragma unroll
      for (int r = 0; r < 4; r++){
        int row = m0 + wm * 64 + mf * 16 + (l >> 4) * 4 + r;
        float sqi = sq[row], mi = mask[row];
        #pragma unroll
        for (int nf = 0; nf < 4; nf++){
          float d2 = sqi + sqc[nf] - 2.f * acc[mf][nf][r];
          acc[mf][nf][r] = sqrtf(fmaxf(d2, 0.f)) * (mi * mkc[nf]) * LOG2E + 8.f;
        }
      }
    }
    // normal-orientation stores + row-max atomics
    #pragma unroll
    for (int mf = 0; mf < 4; mf++){
      #pragma unroll
      for (int r = 0; r < 4; r++){
        int row = m0 + wm * 64 + mf * 16 + (l >> 4) * 4 + r;
        float rm = 0.f;
        #pragma unroll
        for (int nf = 0; nf < 4; nf++){
          int col = n0 + wn * 64 + nf * 16 + (l & 15);
          outb[(size_t)row * Ll + col] = f2bf(acc[mf][nf][r]);
          rm = fmaxf(rm, acc[mf][nf][r]);
        }
        #pragma unroll
        for (int t = 1; t < 16; t <<= 1) rm = fmaxf(rm, __shfl_xor(rm, t, 64));
        if ((l & 15) == 0) atomicMax((int*)(rmax + row), __float_as_int(rm));
      }
    }
    if (bxx != byy){
      // transposed stores (packed 4 rows per uint2) + col-max atomics
      #pragma unroll
      for (int nf = 0; nf < 4; nf++){
        int col = n0 + wn * 64 + nf * 16 + (l & 15);
        float cm = 0.f;
        #pragma unroll
        for (int mf = 0; mf < 4; mf++){
          uint2 pk2;
          pk2.x = (unsigned)f2bf(acc[mf][nf][0]) | ((unsigned)f2bf(acc[mf][nf][1]) << 16);
          pk2.y = (unsigned)f2bf(acc[mf][nf][2]) | ((unsigned)f2bf(acc[mf][nf][3]) << 16);
          int rowb = m0 + wm * 64 + mf * 16 + (l >> 4) * 4;
          *(uint2*)(outb + (size_t)col * Ll + rowb) = pk2;
          cm = fmaxf(cm, fmaxf(fmaxf(acc[mf][nf][0], acc[mf][nf][1]),
                               fmaxf(acc[mf][nf][2], acc[mf][nf][3])));
        }
        cm = fmaxf(cm, __shfl_xor(cm, 16, 64));
        cm = fmaxf(cm, __shfl_xor(cm, 32, 64));
        if ((l >> 4) == 0) atomicMax((int*)(rmax + col), __float_as_int(cm));
      }
    }
  } else {
    #pragma unroll
    for (int mf = 0; mf < 4; mf++){
      #pragma unroll
      for (int r = 0; r < 4; r++){
        int row = m0 + wm * 64 + mf * 16 + (l >> 4) * 4 + r;
        #pragma unroll
        for (int nf = 0; nf < 4; nf++){
          int col = n0 + wn * 64 + nf * 16 + (l & 15);
          float bval;
          if (MODE == 5){
            const float* bp = col < 512 ? bias : (col < 1024 ? bias_k : bias_v);
            bval = bp[col & 511];
          } else {
            bval = bias[col];
          }
          float v = acc[mf][nf][r] + bval;
          if (MODE == 3) outb[(size_t)row * N + col] = f2bf(fmaxf(v, 0.f));
          if (MODE == 5){
            if (col < 1024){
              outb[(size_t)row * N + col] = f2bf(v);
            } else {
              int c = col - 1024;
              int bidx = row >> 11, lpos = row & 2047;
              ((unsigned short*)outf)[(((size_t)bidx * Hh + (c >> 6)) * DHd + (c & 63)) * Ll + lpos] = f2bf(v);
            }
          }
          if (MODE == 2 || MODE == 4)
            outf[(size_t)row * N + col] = v + extra[(size_t)row * N + col];
        }
      }
    }
  }
}

// ---------------------------------------------------------------------------
// flash attention, SWAPPED QK^T, FIXED-m exp2 softmax, QBLK=128 (2 q-sets/wave).
// grid (L/128, H, B) = 512 blocks, block 256 (4 waves x 32 q-rows).
// cdm arrives as cd*LOG2E*mask + 8 (m=8 shift pre-folded): p = 2^(qk*c - cdm').
// K/V fragments read once per tile and shared by both q-sets (halves DS).
// No running max, no rescale, no cross-lane reduce in the hot loop.
__global__ __launch_bounds__(256) void flash_attn(
    const unsigned short* __restrict__ qkv,
    const unsigned short* __restrict__ vT,
    const unsigned short* __restrict__ cdm,   // cd*LOG2E + 8
    const float* __restrict__ rmax,           // max_k of stored cdm
    unsigned short* __restrict__ y)
{
  const int b = blockIdx.z, h = blockIdx.y, q0 = blockIdx.x * 128;
  const int tid = threadIdx.x, w = tid >> 6, l = tid & 63;
  const int ql = l & 15, lg = l >> 4;
  __shared__ unsigned short QPs[128 * 64];   // 16KB: Q staging; reused as P
  __shared__ unsigned short Ks[2][64 * 64];  // 16KB dbuf
  __shared__ unsigned short Vs[2][64 * 64];  // 16KB dbuf

  const int srow = w * 8 + (l >> 3);
  const int sc = l & 7;
  const unsigned short* kbase = qkv + (size_t)b * Ll * 1536 + 512 + h * DHd;
  const unsigned short* vbase = vT + (size_t)(b * Hh + h) * DHd * Ll;

  // prologue: stage Q (128 rows) + tile 0 of K/V
  #pragma unroll
  for (int j = 0; j < 4; j++){
    int row = j * 32 + srow;
    gload16(qkv + (size_t)(b * Ll + q0 + row) * 1536 + h * DHd + ((sc ^ (row & 7)) << 3),
            QPs + j * 2048 + w * 512);
  }
  #pragma unroll
  for (int j = 0; j < 2; j++){
    int row = j * 32 + srow;
    gload16(kbase + (size_t)row * 1536 + ((sc ^ (row & 7)) << 3),
            &Ks[0][0] + j * 2048 + w * 512);
    gload16(vbase + (size_t)row * Ll + ((sc ^ (row & 7)) << 3),
            &Vs[0][0] + j * 2048 + w * 512);
  }

  float rmx[2]; const unsigned short* cdrow[2];
  #pragma unroll
  for (int s = 0; s < 2; s++){
    int qg = q0 + w * 32 + s * 16 + ql;
    rmx[s] = rmax[b * Ll + qg];
    cdrow[s] = cdm + (size_t)(b * Ll + qg) * Ll;
  }
  uint2 cdn[2][4];
  #pragma unroll
  for (int s = 0; s < 2; s++)
    #pragma unroll
    for (int nf = 0; nf < 4; nf++)
      cdn[s][nf] = *(const uint2*)(cdrow[s] + nf * 16 + lg * 4);

  f32x4 o[2][4];
  const f32x4 z4 = {0.f, 0.f, 0.f, 0.f};
  #pragma unroll
  for (int s = 0; s < 2; s++)
    #pragma unroll
    for (int nf = 0; nf < 4; nf++) o[s][nf] = z4;
  float lsum[2] = {0.f, 0.f};

  __syncthreads();   // Q + tile 0 resident

  // hoist Q B-fragments; wave w's Q rows [w*32, w*32+32) == its future P region
  bf16x8 qa[2][2];
  #pragma unroll
  for (int s = 0; s < 2; s++)
    #pragma unroll
    for (int kk = 0; kk < 2; kk++){
      int ra = w * 32 + s * 16 + ql;
      qa[s][kk] = *(const bf16x8*)((const char*)QPs + ra * 128 +
                   (((kk * 4 + lg) ^ (ra & 7)) << 4));
    }

  const int NT = Ll / 64;
  for (int t = 0; t < NT; ++t){
    const int k0 = t * 64;
    const int cur = t & 1;

    if (t + 1 < NT){                  // stage next K/V (overlaps this tile)
      const int kn = k0 + 64;
      #pragma unroll
      for (int j = 0; j < 2; j++){
        int row = j * 32 + srow;
        gload16(kbase + (size_t)(kn + row) * 1536 + ((sc ^ (row & 7)) << 3),
                &Ks[cur ^ 1][0] + j * 2048 + w * 512);
        gload16(vbase + (size_t)row * Ll + kn + ((sc ^ (row & 7)) << 3),
                &Vs[cur ^ 1][0] + j * 2048 + w * 512);
      }
    }

    // S^T = K Q^T, K-frags shared by both q-sets
    f32x4 sa[2][4];
    #pragma unroll
    for (int s = 0; s < 2; s++)
      #pragma unroll
      for (int nf = 0; nf < 4; nf++) sa[s][nf] = z4;
    #pragma unroll
    for (int nf = 0; nf < 4; nf++){
      #pragma unroll
      for (int kk = 0; kk < 2; kk++){
        int rb = nf * 16 + ql;
        bf16x8 kb = *(const bf16x8*)((const char*)Ks[cur] + rb * 128 +
                      (((kk * 4 + lg) ^ (rb & 7)) << 4));
        sa[0][nf] = mfma16(kb, qa[0][kk], sa[0][nf]);
        sa[1][nf] = mfma16(kb, qa[1][kk], sa[1][nf]);
      }
    }

    // fixed-m softmax per set: p = 2^(qk*c - cdm'), diag gets extra -rmax
    #pragma unroll
    for (int s = 0; s < 2; s++){
      float sv[16];
      #pragma unroll
      for (int nf = 0; nf < 4; nf++){
        float c0 = __uint_as_float(cdn[s][nf].x << 16);
        float c1 = __uint_as_float(cdn[s][nf].x & 0xffff0000u);
        float c2 = __uint_as_float(cdn[s][nf].y << 16);
        float c3 = __uint_as_float(cdn[s][nf].y & 0xffff0000u);
        sv[nf * 4 + 0] = fmaf(sa[s][nf][0], 0.125f * LOG2E, -c0);
        sv[nf * 4 + 1] = fmaf(sa[s][nf][1], 0.125f * LOG2E, -c1);
        sv[nf * 4 + 2] = fmaf(sa[s][nf][2], 0.125f * LOG2E, -c2);
        sv[nf * 4 + 3] = fmaf(sa[s][nf][3], 0.125f * LOG2E, -c3);
      }
      if (t + 1 < NT){                // cdn[s] consumed; prefetch next tile
        #pragma unroll
        for (int nf = 0; nf < 4; nf++)
          cdn[s][nf] = *(const uint2*)(cdrow[s] + k0 + 64 + nf * 16 + lg * 4);
      }
      const int dk0 = q0 + ((2 * w + s) >> 2) * 64;
      if (k0 == dk0){                 // diagonal tile for this set
        const int dn = (2 * w + s) & 3;
        #pragma unroll
        for (int r = 0; r < 4; r++)
          if (lg * 4 + r == ql) sv[dn * 4 + r] -= rmx[s];
      }
      float p[16], ps = 0.f;
      #pragma unroll
      for (int i = 0; i < 16; i++){ p[i] = exp2_hw(sv[i]); ps += p[i]; }
      lsum[s] += ps;

      const int rp = s * 16 + ql;
      #pragma unroll
      for (int nf = 0; nf < 4; nf++){
        unsigned d0, d1;
        asm("v_cvt_pk_bf16_f32 %0, %1, %2" : "=v"(d0) : "v"(p[nf*4+0]), "v"(p[nf*4+1]));
        asm("v_cvt_pk_bf16_f32 %0, %1, %2" : "=v"(d1) : "v"(p[nf*4+2]), "v"(p[nf*4+3]));
        uint2 pk2; pk2.x = d0; pk2.y = d1;
        *(uint2*)((char*)QPs + w * 4096 + rp * 128 +
                  ((nf * 32 + lg * 8) ^ ((rp & 7) << 4))) = pk2;
      }
    }

    // PV: A = P (per set), B = V shared across sets
    bf16x8 pa[2][2];
    #pragma unroll
    for (int s = 0; s < 2; s++)
      #pragma unroll
      for (int kk = 0; kk < 2; kk++){
        int rp = s * 16 + ql;
        pa[s][kk] = *(const bf16x8*)((const char*)QPs + w * 4096 + rp * 128 +
                     (((kk * 4 + lg) ^ (rp & 7)) << 4));
      }
    #pragma unroll
    for (int nf = 0; nf < 4; nf++){
      #pragma unroll
      for (int kk = 0; kk < 2; kk++){
        int rv = nf * 16 + ql;
        bf16x8 vb = *(const bf16x8*)((const char*)Vs[cur] + rv * 128 +
                      (((kk * 4 + lg) ^ (rv & 7)) << 4));
        o[0][nf] = mfma16(pa[0][kk], vb, o[0][nf]);
        o[1][nf] = mfma16(pa[1][kk], vb, o[1][nf]);
      }
    }
    __syncthreads();   // staged loads drained; buffers safe to swap
  }

  // epilogue per set: reduce lsum across lg, normalize, store
  #pragma unroll
  for (int s = 0; s < 2; s++){
    float ltot = lsum[s];
    ltot += __shfl_xor(ltot, 16, 64);
    ltot += __shfl_xor(ltot, 32, 64);
    float lf[4];
    #pragma unroll
    for (int r = 0; r < 4; r++)
      lf[r] = __shfl(ltot, (l & 48) | (lg * 4 + r), 64);
    #pragma unroll
    for (int nf = 0; nf < 4; nf++){
      #pragma unroll
      for (int r = 0; r < 4; r++){
        int qo = q0 + w * 32 + s * 16 + lg * 4 + r;
        float v = o[s][nf][r] / lf[r];
        y[(size_t)(b * Ll + qo) * Dd + h * DHd + nf * 16 + ql] = f2bf(v);
      }
    }
  }
}

// ---------------------------------------------------------------------------
// layernorm over D=512.  grid = B*L, block 256 (2 elems/thr)
__global__ __launch_bounds__(256) void ln_kernel(const float* __restrict__ in,
                                                 const float* __restrict__ g,
                                                 const float* __restrict__ bt,
                                                 float* __restrict__ outf,
                                                 unsigned short* __restrict__ outb){
  int row = blockIdx.x, tid = threadIdx.x;
  float2 v = ((const float2*)(in + (size_t)row * Dd))[tid];
  float s = v.x + v.y, s2 = v.x * v.x + v.y * v.y;
  #pragma unroll
  for (int t = 1; t < 64; t <<= 1){ s += __shfl_xor(s, t, 64); s2 += __shfl_xor(s2, t, 64); }
  __shared__ float red[8];
  if ((tid & 63) == 0){ red[tid >> 6] = s; red[4 + (tid >> 6)] = s2; }
  __syncthreads();
  float S  = red[0] + red[1] + red[2] + red[3];
  float S2 = red[4] + red[5] + red[6] + red[7];
  float mu = S * (1.f / 512.f);
  float var = fmaxf(S2 * (1.f / 512.f) - mu * mu, 0.f);
  float rs = rsqrtf(var + 1e-5f);
  int c = tid * 2;
  float o0 = (v.x - mu) * rs * g[c] + bt[c];
  float o1 = (v.y - mu) * rs * g[c + 1] + bt[c + 1];
  float2 ov; ov.x = o0; ov.y = o1;
  ((float2*)(outf + (size_t)row * Dd))[tid] = ov;
  if (outb){
    ((unsigned*)(outb + (size_t)row * Dd))[tid] =
        (unsigned)f2bf(o0) | ((unsigned)f2bf(o1) << 16);
  }
}

// ---------------------------------------------------------------------------
extern "C" void kernel_launch(void* const* d_in, const int* in_sizes, int n_in,
                              void* d_out, int out_size, void* d_ws, size_t ws_size,
                              hipStream_t stream){
  const float* x     = (const float*)d_in[0];
  const float* nmask = (const float*)d_in[1];
  const float* wq = (const float*)d_in[2];  const float* bq = (const float*)d_in[3];
  const float* wk = (const float*)d_in[4];  const float* bk = (const float*)d_in[5];
  const float* wv = (const float*)d_in[6];  const float* bv = (const float*)d_in[7];
  const float* wo = (const float*)d_in[8];  const float* bo = (const float*)d_in[9];
  const float* ln1g = (const float*)d_in[10]; const float* ln1b = (const float*)d_in[11];
  const float* w1 = (const float*)d_in[12]; const float* b1 = (const float*)d_in[13];
  const float* w2 = (const float*)d_in[14]; const float* b2 = (const float*)d_in[15];
  const float* ln2g = (const float*)d_in[16]; const float* ln2b = (const float*)d_in[17];
  float* outp = (float*)d_out;
  char* ws = (char*)d_ws;

  // workspace layout (bytes)
  unsigned short* xbf   = (unsigned short*)(ws + 0);          //  8 MB
  float* sq   = (float*)(ws + 8388608);                       //  32 KB
  float* rmax = (float*)(ws + 8421376);                       //  32 KB
  unsigned short* wqkvT = (unsigned short*)(ws + 8454144);    //  1.5 MB (1536 x 512)
  unsigned short* woT   = (unsigned short*)(ws + 10027008);   //  512 KB
  unsigned short* w1T   = (unsigned short*)(ws + 10551296);   //  2 MB
  unsigned short* w2T   = (unsigned short*)(ws + 12648448);   //  2 MB
  unsigned short* cdm   = (unsigned short*)(ws + 14745600);   // 32 MB (later reused as h1)
  unsigned short* qkv   = (unsigned short*)(ws + 48300032);   // 24 MB (b,l,1536; v-slice unused)
  unsigned short* vT    = (unsigned short*)(ws + 73465856);   //  8 MB
  unsigned short* yb    = (unsigned short*)(ws + 81854464);   //  8 MB
  float* res = (float*)(ws + 90243072);                       // 16 MB (resid1, then resid2)
  float* Xf  = (float*)(ws + 107020288);                      // 16 MB
  unsigned short* h1  = cdm;   // reuse (cdist dead after attention)
  unsigned short* Xbf = qkv;   // reuse (qkv dead after attention)

  hipMemsetAsync(rmax, 0, sizeof(float) * Bb * Ll, stream);

  sumsq_cast<<<Bb * Ll, 256, 0, stream>>>(x, xbf, sq);

  transpose_all<<<3072, dim3(32, 8), 0, stream>>>(wq, wk, wv, wo, w1, w2,
                                                  wqkvT, woT, w1T, w2T);

  // cdist (triangular): Gram + epilogue -> cdm' = cd*log2e + 8, rmax
  gemm_bt<0><<<dim3(136, 1, 4), 256, 0, stream>>>(xbf, xbf, Ll, Ll, Dd,
      nullptr, nullptr, nullptr, cdm, sq, rmax, nmask, nullptr, nullptr);

  // fused QKV projection -> qkv (q,k) + vT (v, transposed) in one pass
  gemm_bt<5><<<dim3(12, 64, 1), 256, 0, stream>>>(xbf, wqkvT, Bb * Ll, 1536, Dd,
      bq, nullptr, (float*)vT, qkv, nullptr, nullptr, nullptr, bk, bv);

  flash_attn<<<dim3(Ll / 128, Hh, Bb), 256, 0, stream>>>(qkv, vT, cdm, rmax, yb);

  // out projection + residual -> resid1 (f32)
  gemm_bt<2><<<dim3(4, 64, 1), 256, 0, stream>>>(yb, woT, Bb * Ll, Dd, Dd,
      bo, x, res, nullptr, nullptr, nullptr, nullptr, nullptr, nullptr);

  ln_kernel<<<Bb * Ll, 256, 0, stream>>>(res, ln1g, ln1b, Xf, Xbf);

  // FFN
  gemm_bt<3><<<dim3(16, 64, 1), 256, 0, stream>>>(Xbf, w1T, Bb * Ll, 4 * Dd, Dd,
      b1, nullptr, nullptr, h1, nullptr, nullptr, nullptr, nullptr, nullptr);
  gemm_bt<4><<<dim3(4, 64, 1), 256, 0, stream>>>(h1, w2T, Bb * Ll, Dd, 4 * Dd,
      b2, Xf, res, nullptr, nullptr, nullptr, nullptr, nullptr, nullptr);

  ln_kernel<<<Bb * Ll, 256, 0, stream>>>(res, ln2g, ln2b, outp, nullptr);
}